// Round 4
// baseline (6161.120 us; speedup 1.0000x reference)
//
#include <hip/hip_runtime.h>
#include <hip/hip_bf16.h>

#define BB 4
#define MM 8192
#define SS1 2048
#define SS2 512

// ---------------- local branch MLP: pos -> 64 -> 64 -> 128 (tanh each) ----------------
// Runs LAST: it overwrites the scratch that lives in the local-output region.
__global__ __launch_bounds__(256) void local_mlp_kernel(
    const float* __restrict__ pos,
    const float* __restrict__ w0, const float* __restrict__ b0,
    const float* __restrict__ w1, const float* __restrict__ b1,
    const float* __restrict__ w2, const float* __restrict__ b2,
    float* __restrict__ out) {
  __shared__ float p[2][3];
  __shared__ float h0[2][64];
  __shared__ float h1[2][64];
  int t = threadIdx.x;
  size_t pid0 = (size_t)blockIdx.x * 2;
  if (t < 6) {
    int pp = t / 3, j = t % 3;
    p[pp][j] = pos[(pid0 + pp) * 3 + j];
  }
  __syncthreads();
  if (t < 128) {
    int pp = t >> 6, c = t & 63;
    float acc = b0[c];
    #pragma unroll
    for (int j = 0; j < 3; ++j) acc += p[pp][j] * w0[j * 64 + c];
    h0[pp][c] = tanhf(acc);
  }
  __syncthreads();
  if (t < 128) {
    int pp = t >> 6, c = t & 63;
    float acc = b1[c];
    #pragma unroll
    for (int j = 0; j < 64; ++j) acc += h0[pp][j] * w1[j * 64 + c];
    h1[pp][c] = tanhf(acc);
  }
  __syncthreads();
  {
    int pp = t >> 7, c = t & 127;
    float acc = b2[c];
    #pragma unroll
    for (int j = 0; j < 64; ++j) acc += h1[pp][j] * w2[j * 128 + c];
    out[(pid0 + pp) * 128 + c] = tanhf(acc);
  }
}

// ---------------- farthest point sampling ----------------
// One block per batch. Exact f32 numpy semantics: no fma in distances,
// argmax ties -> lowest index via packed key (d2_bits<<32)|~idx.
// The winner's coordinates ride along with the key through the reduction.
template <int MP, int NSEL, int THREADS>
__global__ __launch_bounds__(THREADS) void fps_kernel(const float* __restrict__ pts,
                                                      float* __restrict__ cen) {
  constexpr int E = MP / THREADS;
  constexpr int W = THREADS / 64;
  __shared__ unsigned long long kb[2][W];
  __shared__ float kx[2][W], ky[2][W], kz[2][W];
  int t = threadIdx.x;
  int b = blockIdx.x;
  const float* p = pts + (size_t)b * MP * 3;
  float* c_out = cen + (size_t)b * NSEL * 3;
  float px[E], py[E], pz[E], dd[E];
  int base = t * E;
  #pragma unroll
  for (int e = 0; e < E; ++e) {
    px[e] = p[(base + e) * 3 + 0];
    py[e] = p[(base + e) * 3 + 1];
    pz[e] = p[(base + e) * 3 + 2];
    dd[e] = INFINITY;
  }
  float cx = p[0], cy = p[1], cz = p[2];
  if (t == 0) { c_out[0] = cx; c_out[1] = cy; c_out[2] = cz; }
  int par = 0;
  for (int it = 1; it < NSEL; ++it) {
    unsigned long long bk = 0ull;
    float bx = 0.f, by = 0.f, bz = 0.f;
    {
      #pragma clang fp contract(off)
      #pragma unroll
      for (int e = 0; e < E; ++e) {
        float dx = px[e] - cx, dy = py[e] - cy, dz = pz[e] - cz;
        float nd = dx * dx;
        nd += dy * dy;
        nd += dz * dz;
        float d = fminf(dd[e], nd);
        dd[e] = d;
        unsigned long long k =
            ((unsigned long long)__float_as_uint(d) << 32) | (unsigned)(~(base + e));
        if (k > bk) { bk = k; bx = px[e]; by = py[e]; bz = pz[e]; }
      }
    }
    #pragma unroll
    for (int m = 32; m; m >>= 1) {
      unsigned long long ok = __shfl_xor(bk, m, 64);
      float ox = __shfl_xor(bx, m, 64);
      float oy = __shfl_xor(by, m, 64);
      float oz = __shfl_xor(bz, m, 64);
      if (ok > bk) { bk = ok; bx = ox; by = oy; bz = oz; }
    }
    if ((t & 63) == 0) {
      int w = t >> 6;
      kb[par][w] = bk;
      kx[par][w] = bx; ky[par][w] = by; kz[par][w] = bz;
    }
    __syncthreads();
    unsigned long long g = kb[par][0];
    cx = kx[par][0]; cy = ky[par][0]; cz = kz[par][0];
    #pragma unroll
    for (int w = 1; w < W; ++w) {
      unsigned long long o = kb[par][w];
      if (o > g) { g = o; cx = kx[par][w]; cy = ky[par][w]; cz = kz[par][w]; }
    }
    if (t == 0) {
      c_out[it * 3 + 0] = cx;
      c_out[it * 3 + 1] = cy;
      c_out[it * 3 + 2] = cz;
    }
    par ^= 1;
  }
}

// ---------------- ball query: 64 nearest with d2 <= R2, ties by lower index ----------------
// One wave per center; ballot compaction into LDS, then iterative wave-min selection.
template <int MP>
__global__ __launch_bounds__(256) void nbr_kernel(const float* __restrict__ pts,
                                                  const float* __restrict__ cen, int S,
                                                  float R2, int* __restrict__ nbr) {
  constexpr int CAP = 1024;
  __shared__ unsigned long long buf[4][CAP];
  int t = threadIdx.x;
  int wv = t >> 6, lane = t & 63;
  int gw = blockIdx.x * 4 + wv;
  int b = gw / S, s = gw % S;
  const float* p = pts + (size_t)b * MP * 3;
  const float* c = cen + ((size_t)b * S + s) * 3;
  float cx = c[0], cy = c[1], cz = c[2];
  unsigned long long* bw = buf[wv];
  int cnt = 0;
  {
    #pragma clang fp contract(off)
    for (int i0 = 0; i0 < MP; i0 += 64) {
      int i = i0 + lane;
      float dx = p[i * 3 + 0] - cx;
      float dy = p[i * 3 + 1] - cy;
      float dz = p[i * 3 + 2] - cz;
      float d2 = dx * dx;
      d2 += dy * dy;
      d2 += dz * dz;
      bool in = (d2 <= R2);
      unsigned long long mask = __ballot(in);
      if (in) {
        int off = __popcll(mask & ((1ull << lane) - 1ull));
        int pos = cnt + off;
        if (pos < CAP)
          bw[pos] = ((unsigned long long)__float_as_uint(d2) << 32) | (unsigned)i;
      }
      cnt += __popcll(mask);
    }
  }
  if (cnt > CAP) cnt = CAP;
  __syncthreads();  // uniform; ensures LDS writes visible
  int out = -1;
  if (cnt <= 64) {
    if (lane < cnt) out = (int)(unsigned)bw[lane];
  } else {
    for (int r = 0; r < 64; ++r) {
      unsigned long long mk = ~0ull;
      int mj = -1;
      for (int j = lane; j < cnt; j += 64) {
        unsigned long long v = bw[j];
        if (v < mk) { mk = v; mj = j; }
      }
      unsigned long long g = mk;
      #pragma unroll
      for (int m = 32; m; m >>= 1) {
        unsigned long long o = __shfl_xor(g, m, 64);
        g = g < o ? g : o;
      }
      if (mk == g && mj >= 0) bw[mj] = ~0ull;  // unique keys -> exactly one owner
      asm volatile("s_waitcnt lgkmcnt(0)" ::: "memory");
      if (lane == r) out = (int)(unsigned)g;
    }
  }
  nbr[((size_t)b * S + s) * 64 + lane] = out;
}

// ---------------- SA1 grouped MLP: feats[64][9] -> 64 -> 128, masked max over K ----------------
__global__ __launch_bounds__(128) void group1_kernel(
    const float* __restrict__ pos, const float* __restrict__ x,
    const float* __restrict__ c1, const int* __restrict__ nbr,
    const float* __restrict__ w0, const float* __restrict__ b0,
    const float* __restrict__ w1, const float* __restrict__ b1,
    float* __restrict__ h1out) {
  __shared__ float feats[64][12];
  __shared__ float hbuf[64][66];
  __shared__ int nb[64];
  __shared__ float cc[3];
  int t = threadIdx.x;
  int bs = blockIdx.x;  // b*S1 + s
  int b = bs >> 11;
  if (t < 64) nb[t] = nbr[(size_t)bs * 64 + t];
  if (t < 3) cc[t] = c1[(size_t)bs * 3 + t];
  __syncthreads();
  if (t < 64) {
    int n = nb[t];
    int ni = n >= 0 ? n : 0;
    const float* pp = pos + ((size_t)b * MM + ni) * 3;
    const float* xx = x + ((size_t)b * MM + ni) * 3;
    float p0 = pp[0], p1 = pp[1], p2 = pp[2];
    feats[t][0] = p0; feats[t][1] = p1; feats[t][2] = p2;
    feats[t][3] = xx[0]; feats[t][4] = xx[1]; feats[t][5] = xx[2];
    feats[t][6] = p0 - cc[0]; feats[t][7] = p1 - cc[1]; feats[t][8] = p2 - cc[2];
  }
  __syncthreads();
  // layer1: 9 -> 64; thread -> (k = t>>1, q = t&1), 32 channels each
  {
    int k = t >> 1, q = t & 1;
    float acc[32];
    #pragma unroll
    for (int i = 0; i < 32; ++i) acc[i] = b0[q * 32 + i];
    #pragma unroll
    for (int j = 0; j < 9; ++j) {
      float f = feats[k][j];
      #pragma unroll
      for (int i = 0; i < 32; ++i) acc[i] += f * w0[j * 64 + q * 32 + i];
    }
    #pragma unroll
    for (int i = 0; i < 32; ++i) hbuf[k][q * 32 + i] = tanhf(acc[i]);
  }
  __syncthreads();
  // layer2: 64 -> 128 + masked max over k
  {
    int ch = t;  // 0..127
    float w[64];
    #pragma unroll
    for (int j = 0; j < 64; ++j) w[j] = w1[j * 128 + ch];
    float bias = b1[ch];
    float mx = -INFINITY;
    for (int k = 0; k < 64; ++k) {
      if (nb[k] < 0) continue;  // uniform across block
      float a = bias;
      #pragma unroll
      for (int j = 0; j < 64; ++j) a += hbuf[k][j] * w[j];
      mx = fmaxf(mx, tanhf(a));
    }
    h1out[(size_t)bs * 128 + ch] = mx;
  }
}

// ---------------- SA2 grouped MLP: feats[64][131] -> 128 -> 256, masked max over K ----------------
__global__ __launch_bounds__(256) void group2_kernel(
    const float* __restrict__ h1, const float* __restrict__ c1,
    const float* __restrict__ c2, const int* __restrict__ nbr,
    const float* __restrict__ w0, const float* __restrict__ b0,
    const float* __restrict__ w1, const float* __restrict__ b1,
    float* __restrict__ h2out) {
  __shared__ float fb[64][132];  // feats (131) then reused as hidden (128)
  __shared__ int nb[64];
  __shared__ float cc[3];
  int t = threadIdx.x;
  int bs = blockIdx.x;  // b*S2 + s
  int b = bs >> 9;
  if (t < 64) nb[t] = nbr[(size_t)bs * 64 + t];
  if (t < 3) cc[t] = c2[(size_t)bs * 3 + t];
  __syncthreads();
  {
    int k = t >> 2, q = t & 3;
    int n = nb[k];
    int ni = n >= 0 ? n : 0;
    const float* hrow = h1 + ((size_t)b * SS1 + ni) * 128;
    #pragma unroll
    for (int i = 0; i < 32; ++i) fb[k][q * 32 + i] = hrow[q * 32 + i];
    if (q == 0) {
      const float* pr = c1 + ((size_t)b * SS1 + ni) * 3;
      fb[k][128] = pr[0] - cc[0];
      fb[k][129] = pr[1] - cc[1];
      fb[k][130] = pr[2] - cc[2];
    }
  }
  __syncthreads();
  // layer1: 131 -> 128; thread -> (k = t>>2, q = t&3), 32 channels each
  float acc[32];
  {
    int k = t >> 2, q = t & 3;
    #pragma unroll
    for (int i = 0; i < 32; ++i) acc[i] = b0[q * 32 + i];
    for (int j = 0; j < 131; ++j) {
      float f = fb[k][j];
      const float* wr = w0 + (size_t)j * 128 + q * 32;
      #pragma unroll
      for (int i = 0; i < 32; ++i) acc[i] += f * wr[i];
    }
  }
  __syncthreads();  // all reads of feats done
  {
    int k = t >> 2, q = t & 3;
    #pragma unroll
    for (int i = 0; i < 32; ++i) fb[k][q * 32 + i] = tanhf(acc[i]);
  }
  __syncthreads();
  // layer2: 128 -> 256 + masked max over k
  {
    int ch = t;  // 0..255
    float w[128];
    #pragma unroll
    for (int j = 0; j < 128; ++j) w[j] = w1[(size_t)j * 256 + ch];
    float bias = b1[ch];
    float mx = -INFINITY;
    for (int k = 0; k < 64; ++k) {
      if (nb[k] < 0) continue;
      float a = bias;
      #pragma unroll
      for (int j = 0; j < 128; ++j) a += fb[k][j] * w[j];
      mx = fmaxf(mx, tanhf(a));
    }
    h2out[(size_t)bs * 256 + ch] = mx;
  }
}

// ---------------- global max over centers ----------------
__global__ __launch_bounds__(256) void gmax_kernel(const float* __restrict__ h2,
                                                   float* __restrict__ out) {
  int b = blockIdx.x, c = threadIdx.x;
  float mx = -INFINITY;
  for (int s = 0; s < SS2; ++s)
    mx = fmaxf(mx, h2[((size_t)b * SS2 + s) * 256 + c]);
  out[(size_t)BB * MM * 128 + b * 256 + c] = mx;
}

extern "C" void kernel_launch(void* const* d_in, const int* in_sizes, int n_in,
                              void* d_out, int out_size, void* d_ws, size_t ws_size,
                              hipStream_t stream) {
  // Reference is pure float32: all inputs AND the output buffer are f32.
  const float* x    = (const float*)d_in[0];
  const float* pos  = (const float*)d_in[1];
  const float* lw0  = (const float*)d_in[2];
  const float* lb0  = (const float*)d_in[3];
  const float* lw1  = (const float*)d_in[4];
  const float* lb1  = (const float*)d_in[5];
  const float* lw2  = (const float*)d_in[6];
  const float* lb2  = (const float*)d_in[7];
  const float* g1w0 = (const float*)d_in[8];
  const float* g1b0 = (const float*)d_in[9];
  const float* g1w1 = (const float*)d_in[10];
  const float* g1b1 = (const float*)d_in[11];
  const float* g2w0 = (const float*)d_in[12];
  const float* g2b0 = (const float*)d_in[13];
  const float* g2w1 = (const float*)d_in[14];
  const float* g2b1 = (const float*)d_in[15];
  float* out = (float*)d_out;

  // Scratch lives inside the LOCAL output region of d_out (4,194,304 f32 =
  // 16,777,216 bytes); local_mlp_kernel runs LAST and overwrites all of it.
  // d_ws is not used (ws_size not guaranteed sufficient).
  char* sc = (char*)d_out;
  float* h1   = (float*)(sc + 0);        // 4*2048*128 f32 = 4,194,304 B
  float* h2   = (float*)(sc + 4194304);  // 4*512*256 f32  = 2,097,152 B
  float* c1   = (float*)(sc + 6291456);  // 4*2048*3 f32   =    98,304 B
  float* c2   = (float*)(sc + 6389760);  // 4*512*3 f32    =    24,576 B
  int*   nbr1 = (int*)(sc + 6414336);    // 4*2048*64 i32  = 2,097,152 B
  int*   nbr2 = (int*)(sc + 8511488);    // 4*512*64 i32   =   524,288 B (end 9,035,776)

  fps_kernel<MM, SS1, 512><<<BB, 512, 0, stream>>>(pos, c1);
  nbr_kernel<MM><<<BB * SS1 / 4, 256, 0, stream>>>(pos, c1, SS1, 0.04f, nbr1);
  group1_kernel<<<BB * SS1, 128, 0, stream>>>(pos, x, c1, nbr1, g1w0, g1b0, g1w1, g1b1, h1);
  fps_kernel<SS1, SS2, 512><<<BB, 512, 0, stream>>>(c1, c2);
  nbr_kernel<SS1><<<BB * SS2 / 4, 256, 0, stream>>>(c1, c2, SS2, 0.16f, nbr2);
  group2_kernel<<<BB * SS2, 256, 0, stream>>>(h1, c1, c2, nbr2, g2w0, g2b0, g2w1, g2b1, h2);
  gmax_kernel<<<BB, 256, 0, stream>>>(h2, out);
  local_mlp_kernel<<<BB * MM / 2, 256, 0, stream>>>(pos, lw0, lb0, lw1, lb1, lw2, lb2, out);
}

// Round 5
// 4553.374 us; speedup vs baseline: 1.3531x; 1.3531x over previous
//
#include <hip/hip_runtime.h>
#include <hip/hip_bf16.h>

#define BB 4
#define MM 8192
#define SS1 2048
#define SS2 512

// ---------------- local branch MLP: pos -> 64 -> 64 -> 128 (tanh each) ----------------
// Runs LAST: it overwrites the scratch that lives in the local-output region.
__global__ __launch_bounds__(256) void local_mlp_kernel(
    const float* __restrict__ pos,
    const float* __restrict__ w0, const float* __restrict__ b0,
    const float* __restrict__ w1, const float* __restrict__ b1,
    const float* __restrict__ w2, const float* __restrict__ b2,
    float* __restrict__ out) {
  __shared__ float p[2][3];
  __shared__ float h0[2][64];
  __shared__ float h1[2][64];
  int t = threadIdx.x;
  size_t pid0 = (size_t)blockIdx.x * 2;
  if (t < 6) {
    int pp = t / 3, j = t % 3;
    p[pp][j] = pos[(pid0 + pp) * 3 + j];
  }
  __syncthreads();
  if (t < 128) {
    int pp = t >> 6, c = t & 63;
    float acc = b0[c];
    #pragma unroll
    for (int j = 0; j < 3; ++j) acc += p[pp][j] * w0[j * 64 + c];
    h0[pp][c] = tanhf(acc);
  }
  __syncthreads();
  if (t < 128) {
    int pp = t >> 6, c = t & 63;
    float acc = b1[c];
    #pragma unroll
    for (int j = 0; j < 64; ++j) acc += h0[pp][j] * w1[j * 64 + c];
    h1[pp][c] = tanhf(acc);
  }
  __syncthreads();
  {
    int pp = t >> 7, c = t & 127;
    float acc = b2[c];
    #pragma unroll
    for (int j = 0; j < 64; ++j) acc += h1[pp][j] * w2[j * 128 + c];
    out[(pid0 + pp) * 128 + c] = tanhf(acc);
  }
}

// ---------------- DPP helpers: full-wave max of a u64 key, result in lane 63 ----------
template <int CTRL>
__device__ __forceinline__ void dpp_max_step(unsigned long long& k) {
  unsigned lo = (unsigned)k, hi = (unsigned)(k >> 32);
  // bound_ctrl=true: out-of-range source lanes read 0; 0 never wins the max
  // (any real key has ~idx low bits != 0).
  unsigned plo = (unsigned)__builtin_amdgcn_update_dpp(0, (int)lo, CTRL, 0xF, 0xF, true);
  unsigned phi = (unsigned)__builtin_amdgcn_update_dpp(0, (int)hi, CTRL, 0xF, 0xF, true);
  unsigned long long pk = ((unsigned long long)phi << 32) | plo;
  if (pk > k) k = pk;
}

__device__ __forceinline__ void wave_max_u64(unsigned long long& k) {
  dpp_max_step<0x111>(k);  // row_shr:1
  dpp_max_step<0x112>(k);  // row_shr:2
  dpp_max_step<0x114>(k);  // row_shr:4
  dpp_max_step<0x118>(k);  // row_shr:8  -> lane 15 of each row holds row max
  dpp_max_step<0x142>(k);  // row_bcast:15 -> lane31=max(r0,r1), lane63=max(r2,r3)
  dpp_max_step<0x143>(k);  // row_bcast:31 -> lane63 = wave max
}

// ---------------- farthest point sampling ----------------
// One block per batch. Exact f32 numpy semantics: no fma in distances (contract off,
// left-to-right x+y then +z), argmax ties -> lowest index via packed key
// (d2_bits<<32)|~idx (d2 >= 0 so bit pattern is order-isomorphic).
// Per-thread best tracked as (float,int); u64 key packed ONCE per iteration;
// wave reduce via DPP (ALU latency, no ds_bpermute); winner coords re-fetched
// from global (wave-uniform address -> scalar load, L2-resident).
template <int MP, int NSEL, int THREADS>
__global__ __launch_bounds__(THREADS, 1) void fps_kernel(const float* __restrict__ pts,
                                                         float* __restrict__ cen) {
  constexpr int E = MP / THREADS;
  constexpr int W = THREADS / 64;
  __shared__ unsigned long long kb[2][W];
  int t = threadIdx.x;
  int lane = t & 63, wv = t >> 6;
  int b = blockIdx.x;
  const float* p = pts + (size_t)b * MP * 3;
  float* c_out = cen + (size_t)b * NSEL * 3;
  float px[E], py[E], pz[E], dd[E];
  int base = t * E;
  #pragma unroll
  for (int e = 0; e < E; ++e) {
    px[e] = p[(base + e) * 3 + 0];
    py[e] = p[(base + e) * 3 + 1];
    pz[e] = p[(base + e) * 3 + 2];
    dd[e] = INFINITY;
  }
  float cx = p[0], cy = p[1], cz = p[2];
  if (t == 0) { c_out[0] = cx; c_out[1] = cy; c_out[2] = cz; }
  int par = 0;
  for (int it = 1; it < NSEL; ++it) {
    float bd = -1.0f;
    int bidx = 0;
    {
      #pragma clang fp contract(off)
      #pragma unroll
      for (int e = 0; e < E; ++e) {
        float dx = px[e] - cx, dy = py[e] - cy, dz = pz[e] - cz;
        float nd = dx * dx;
        nd += dy * dy;
        nd += dz * dz;
        float d = fminf(dd[e], nd);
        dd[e] = d;
        if (d > bd) { bd = d; bidx = base + e; }  // strict > keeps lowest index on ties
      }
    }
    unsigned long long k =
        ((unsigned long long)__float_as_uint(bd) << 32) | (unsigned)(~bidx);
    wave_max_u64(k);
    if (lane == 63) kb[par][wv] = k;
    __syncthreads();
    unsigned long long g = kb[par][0];
    #pragma unroll
    for (int w = 1; w < W; ++w) {
      unsigned long long o = kb[par][w];
      if (o > g) g = o;
    }
    int widx = __builtin_amdgcn_readfirstlane((int)(~(unsigned)g));
    const float* cp = p + (size_t)widx * 3;
    cx = cp[0]; cy = cp[1]; cz = cp[2];
    if (t == 0) {
      c_out[it * 3 + 0] = cx;
      c_out[it * 3 + 1] = cy;
      c_out[it * 3 + 2] = cz;
    }
    par ^= 1;
  }
}

// ---------------- ball query: 64 nearest with d2 <= R2, ties by lower index ----------------
// One wave per center; ballot compaction into LDS, then iterative wave-min selection.
template <int MP>
__global__ __launch_bounds__(256) void nbr_kernel(const float* __restrict__ pts,
                                                  const float* __restrict__ cen, int S,
                                                  float R2, int* __restrict__ nbr) {
  constexpr int CAP = 1024;
  __shared__ unsigned long long buf[4][CAP];
  int t = threadIdx.x;
  int wv = t >> 6, lane = t & 63;
  int gw = blockIdx.x * 4 + wv;
  int b = gw / S, s = gw % S;
  const float* p = pts + (size_t)b * MP * 3;
  const float* c = cen + ((size_t)b * S + s) * 3;
  float cx = c[0], cy = c[1], cz = c[2];
  unsigned long long* bw = buf[wv];
  int cnt = 0;
  {
    #pragma clang fp contract(off)
    for (int i0 = 0; i0 < MP; i0 += 64) {
      int i = i0 + lane;
      float dx = p[i * 3 + 0] - cx;
      float dy = p[i * 3 + 1] - cy;
      float dz = p[i * 3 + 2] - cz;
      float d2 = dx * dx;
      d2 += dy * dy;
      d2 += dz * dz;
      bool in = (d2 <= R2);
      unsigned long long mask = __ballot(in);
      if (in) {
        int off = __popcll(mask & ((1ull << lane) - 1ull));
        int pos = cnt + off;
        if (pos < CAP)
          bw[pos] = ((unsigned long long)__float_as_uint(d2) << 32) | (unsigned)i;
      }
      cnt += __popcll(mask);
    }
  }
  if (cnt > CAP) cnt = CAP;
  __syncthreads();  // uniform; ensures LDS writes visible
  int out = -1;
  if (cnt <= 64) {
    if (lane < cnt) out = (int)(unsigned)bw[lane];
  } else {
    for (int r = 0; r < 64; ++r) {
      unsigned long long mk = ~0ull;
      int mj = -1;
      for (int j = lane; j < cnt; j += 64) {
        unsigned long long v = bw[j];
        if (v < mk) { mk = v; mj = j; }
      }
      unsigned long long g = mk;
      #pragma unroll
      for (int m = 32; m; m >>= 1) {
        unsigned long long o = __shfl_xor(g, m, 64);
        g = g < o ? g : o;
      }
      if (mk == g && mj >= 0) bw[mj] = ~0ull;  // unique keys -> exactly one owner
      asm volatile("s_waitcnt lgkmcnt(0)" ::: "memory");
      if (lane == r) out = (int)(unsigned)g;
    }
  }
  nbr[((size_t)b * S + s) * 64 + lane] = out;
}

// ---------------- SA1 grouped MLP: feats[64][9] -> 64 -> 128, masked max over K ----------------
__global__ __launch_bounds__(128) void group1_kernel(
    const float* __restrict__ pos, const float* __restrict__ x,
    const float* __restrict__ c1, const int* __restrict__ nbr,
    const float* __restrict__ w0, const float* __restrict__ b0,
    const float* __restrict__ w1, const float* __restrict__ b1,
    float* __restrict__ h1out) {
  __shared__ float feats[64][12];
  __shared__ float hbuf[64][66];
  __shared__ int nb[64];
  __shared__ float cc[3];
  int t = threadIdx.x;
  int bs = blockIdx.x;  // b*S1 + s
  int b = bs >> 11;
  if (t < 64) nb[t] = nbr[(size_t)bs * 64 + t];
  if (t < 3) cc[t] = c1[(size_t)bs * 3 + t];
  __syncthreads();
  if (t < 64) {
    int n = nb[t];
    int ni = n >= 0 ? n : 0;
    const float* pp = pos + ((size_t)b * MM + ni) * 3;
    const float* xx = x + ((size_t)b * MM + ni) * 3;
    float p0 = pp[0], p1 = pp[1], p2 = pp[2];
    feats[t][0] = p0; feats[t][1] = p1; feats[t][2] = p2;
    feats[t][3] = xx[0]; feats[t][4] = xx[1]; feats[t][5] = xx[2];
    feats[t][6] = p0 - cc[0]; feats[t][7] = p1 - cc[1]; feats[t][8] = p2 - cc[2];
  }
  __syncthreads();
  // layer1: 9 -> 64; thread -> (k = t>>1, q = t&1), 32 channels each
  {
    int k = t >> 1, q = t & 1;
    float acc[32];
    #pragma unroll
    for (int i = 0; i < 32; ++i) acc[i] = b0[q * 32 + i];
    #pragma unroll
    for (int j = 0; j < 9; ++j) {
      float f = feats[k][j];
      #pragma unroll
      for (int i = 0; i < 32; ++i) acc[i] += f * w0[j * 64 + q * 32 + i];
    }
    #pragma unroll
    for (int i = 0; i < 32; ++i) hbuf[k][q * 32 + i] = tanhf(acc[i]);
  }
  __syncthreads();
  // layer2: 64 -> 128 + masked max over k
  {
    int ch = t;  // 0..127
    float w[64];
    #pragma unroll
    for (int j = 0; j < 64; ++j) w[j] = w1[j * 128 + ch];
    float bias = b1[ch];
    float mx = -INFINITY;
    for (int k = 0; k < 64; ++k) {
      if (nb[k] < 0) continue;  // uniform across block
      float a = bias;
      #pragma unroll
      for (int j = 0; j < 64; ++j) a += hbuf[k][j] * w[j];
      mx = fmaxf(mx, tanhf(a));
    }
    h1out[(size_t)bs * 128 + ch] = mx;
  }
}

// ---------------- SA2 grouped MLP: feats[64][131] -> 128 -> 256, masked max over K ----------------
__global__ __launch_bounds__(256) void group2_kernel(
    const float* __restrict__ h1, const float* __restrict__ c1,
    const float* __restrict__ c2, const int* __restrict__ nbr,
    const float* __restrict__ w0, const float* __restrict__ b0,
    const float* __restrict__ w1, const float* __restrict__ b1,
    float* __restrict__ h2out) {
  __shared__ float fb[64][132];  // feats (131) then reused as hidden (128)
  __shared__ int nb[64];
  __shared__ float cc[3];
  int t = threadIdx.x;
  int bs = blockIdx.x;  // b*S2 + s
  int b = bs >> 9;
  if (t < 64) nb[t] = nbr[(size_t)bs * 64 + t];
  if (t < 3) cc[t] = c2[(size_t)bs * 3 + t];
  __syncthreads();
  {
    int k = t >> 2, q = t & 3;
    int n = nb[k];
    int ni = n >= 0 ? n : 0;
    const float* hrow = h1 + ((size_t)b * SS1 + ni) * 128;
    #pragma unroll
    for (int i = 0; i < 32; ++i) fb[k][q * 32 + i] = hrow[q * 32 + i];
    if (q == 0) {
      const float* pr = c1 + ((size_t)b * SS1 + ni) * 3;
      fb[k][128] = pr[0] - cc[0];
      fb[k][129] = pr[1] - cc[1];
      fb[k][130] = pr[2] - cc[2];
    }
  }
  __syncthreads();
  // layer1: 131 -> 128; thread -> (k = t>>2, q = t&3), 32 channels each
  float acc[32];
  {
    int k = t >> 2, q = t & 3;
    #pragma unroll
    for (int i = 0; i < 32; ++i) acc[i] = b0[q * 32 + i];
    for (int j = 0; j < 131; ++j) {
      float f = fb[k][j];
      const float* wr = w0 + (size_t)j * 128 + q * 32;
      #pragma unroll
      for (int i = 0; i < 32; ++i) acc[i] += f * wr[i];
    }
  }
  __syncthreads();  // all reads of feats done
  {
    int k = t >> 2, q = t & 3;
    #pragma unroll
    for (int i = 0; i < 32; ++i) fb[k][q * 32 + i] = tanhf(acc[i]);
  }
  __syncthreads();
  // layer2: 128 -> 256 + masked max over k
  {
    int ch = t;  // 0..255
    float w[128];
    #pragma unroll
    for (int j = 0; j < 128; ++j) w[j] = w1[(size_t)j * 256 + ch];
    float bias = b1[ch];
    float mx = -INFINITY;
    for (int k = 0; k < 64; ++k) {
      if (nb[k] < 0) continue;
      float a = bias;
      #pragma unroll
      for (int j = 0; j < 128; ++j) a += fb[k][j] * w[j];
      mx = fmaxf(mx, tanhf(a));
    }
    h2out[(size_t)bs * 256 + ch] = mx;
  }
}

// ---------------- global max over centers ----------------
__global__ __launch_bounds__(256) void gmax_kernel(const float* __restrict__ h2,
                                                   float* __restrict__ out) {
  int b = blockIdx.x, c = threadIdx.x;
  float mx = -INFINITY;
  for (int s = 0; s < SS2; ++s)
    mx = fmaxf(mx, h2[((size_t)b * SS2 + s) * 256 + c]);
  out[(size_t)BB * MM * 128 + b * 256 + c] = mx;
}

extern "C" void kernel_launch(void* const* d_in, const int* in_sizes, int n_in,
                              void* d_out, int out_size, void* d_ws, size_t ws_size,
                              hipStream_t stream) {
  // Reference is pure float32: all inputs AND the output buffer are f32.
  const float* x    = (const float*)d_in[0];
  const float* pos  = (const float*)d_in[1];
  const float* lw0  = (const float*)d_in[2];
  const float* lb0  = (const float*)d_in[3];
  const float* lw1  = (const float*)d_in[4];
  const float* lb1  = (const float*)d_in[5];
  const float* lw2  = (const float*)d_in[6];
  const float* lb2  = (const float*)d_in[7];
  const float* g1w0 = (const float*)d_in[8];
  const float* g1b0 = (const float*)d_in[9];
  const float* g1w1 = (const float*)d_in[10];
  const float* g1b1 = (const float*)d_in[11];
  const float* g2w0 = (const float*)d_in[12];
  const float* g2b0 = (const float*)d_in[13];
  const float* g2w1 = (const float*)d_in[14];
  const float* g2b1 = (const float*)d_in[15];
  float* out = (float*)d_out;

  // Scratch lives inside the LOCAL output region of d_out (4,194,304 f32 =
  // 16,777,216 bytes); local_mlp_kernel runs LAST and overwrites all of it.
  // d_ws is not used (ws_size not guaranteed sufficient).
  char* sc = (char*)d_out;
  float* h1   = (float*)(sc + 0);        // 4*2048*128 f32 = 4,194,304 B
  float* h2   = (float*)(sc + 4194304);  // 4*512*256 f32  = 2,097,152 B
  float* c1   = (float*)(sc + 6291456);  // 4*2048*3 f32   =    98,304 B
  float* c2   = (float*)(sc + 6389760);  // 4*512*3 f32    =    24,576 B
  int*   nbr1 = (int*)(sc + 6414336);    // 4*2048*64 i32  = 2,097,152 B
  int*   nbr2 = (int*)(sc + 8511488);    // 4*512*64 i32   =   524,288 B (end 9,035,776)

  fps_kernel<MM, SS1, 256><<<BB, 256, 0, stream>>>(pos, c1);
  nbr_kernel<MM><<<BB * SS1 / 4, 256, 0, stream>>>(pos, c1, SS1, 0.04f, nbr1);
  group1_kernel<<<BB * SS1, 128, 0, stream>>>(pos, x, c1, nbr1, g1w0, g1b0, g1w1, g1b1, h1);
  fps_kernel<SS1, SS2, 256><<<BB, 256, 0, stream>>>(c1, c2);
  nbr_kernel<SS1><<<BB * SS2 / 4, 256, 0, stream>>>(c1, c2, SS2, 0.16f, nbr2);
  group2_kernel<<<BB * SS2, 256, 0, stream>>>(h1, c1, c2, nbr2, g2w0, g2b0, g2w1, g2b1, h2);
  gmax_kernel<<<BB, 256, 0, stream>>>(h2, out);
  local_mlp_kernel<<<BB * MM / 2, 256, 0, stream>>>(pos, lw0, lb0, lw1, lb1, lw2, lb2, out);
}

// Round 6
// 4402.177 us; speedup vs baseline: 1.3996x; 1.0343x over previous
//
#include <hip/hip_runtime.h>
#include <hip/hip_bf16.h>

#define BB 4
#define MM 8192
#define SS1 2048
#define SS2 512

// ---------------- local branch MLP: pos -> 64 -> 64 -> 128 (tanh each) ----------------
// Runs LAST: it overwrites the scratch that lives in the local-output region.
__global__ __launch_bounds__(256) void local_mlp_kernel(
    const float* __restrict__ pos,
    const float* __restrict__ w0, const float* __restrict__ b0,
    const float* __restrict__ w1, const float* __restrict__ b1,
    const float* __restrict__ w2, const float* __restrict__ b2,
    float* __restrict__ out) {
  __shared__ float p[2][3];
  __shared__ float h0[2][64];
  __shared__ float h1[2][64];
  int t = threadIdx.x;
  size_t pid0 = (size_t)blockIdx.x * 2;
  if (t < 6) {
    int pp = t / 3, j = t % 3;
    p[pp][j] = pos[(pid0 + pp) * 3 + j];
  }
  __syncthreads();
  if (t < 128) {
    int pp = t >> 6, c = t & 63;
    float acc = b0[c];
    #pragma unroll
    for (int j = 0; j < 3; ++j) acc += p[pp][j] * w0[j * 64 + c];
    h0[pp][c] = tanhf(acc);
  }
  __syncthreads();
  if (t < 128) {
    int pp = t >> 6, c = t & 63;
    float acc = b1[c];
    #pragma unroll
    for (int j = 0; j < 64; ++j) acc += h0[pp][j] * w1[j * 64 + c];
    h1[pp][c] = tanhf(acc);
  }
  __syncthreads();
  {
    int pp = t >> 7, c = t & 127;
    float acc = b2[c];
    #pragma unroll
    for (int j = 0; j < 64; ++j) acc += h1[pp][j] * w2[j * 128 + c];
    out[(pid0 + pp) * 128 + c] = tanhf(acc);
  }
}

// ---------------- DPP helpers: full-wave max of a u64 key, result in lane 63 ----------
template <int CTRL>
__device__ __forceinline__ void dpp_max_step(unsigned long long& k) {
  unsigned lo = (unsigned)k, hi = (unsigned)(k >> 32);
  // bound_ctrl=true: out-of-range source lanes read 0; 0 never wins the max
  // (any real key in max-domain has nonzero low bits).
  unsigned plo = (unsigned)__builtin_amdgcn_update_dpp(0, (int)lo, CTRL, 0xF, 0xF, true);
  unsigned phi = (unsigned)__builtin_amdgcn_update_dpp(0, (int)hi, CTRL, 0xF, 0xF, true);
  unsigned long long pk = ((unsigned long long)phi << 32) | plo;
  if (pk > k) k = pk;
}

__device__ __forceinline__ void wave_max_u64(unsigned long long& k) {
  dpp_max_step<0x111>(k);  // row_shr:1
  dpp_max_step<0x112>(k);  // row_shr:2
  dpp_max_step<0x114>(k);  // row_shr:4
  dpp_max_step<0x118>(k);  // row_shr:8  -> lane 15 of each row holds row max
  dpp_max_step<0x142>(k);  // row_bcast:15 -> lane31=max(r0,r1), lane63=max(r2,r3)
  dpp_max_step<0x143>(k);  // row_bcast:31 -> lane63 = wave max
}

// ---------------- farthest point sampling ----------------
// One block per batch. Exact f32 numpy semantics: no fma in distances (contract off,
// left-to-right x+y then +z), argmax ties -> lowest index via packed key
// (d2_bits<<32)|~idx (d2 >= 0 so bit pattern is order-isomorphic).
// THREADS=512 so per-thread arrays (4*E VGPRs) stay in registers (E=16 -> 64 VGPRs;
// E=32 at 256 threads spilled to scratch: R5 VGPR_Count=84 < 128 needed).
template <int MP, int NSEL, int THREADS>
__global__ __launch_bounds__(THREADS, 1) void fps_kernel(const float* __restrict__ pts,
                                                         float* __restrict__ cen) {
  constexpr int E = MP / THREADS;
  constexpr int W = THREADS / 64;
  __shared__ unsigned long long kb[2][W];
  int t = threadIdx.x;
  int lane = t & 63, wv = t >> 6;
  int b = blockIdx.x;
  const float* p = pts + (size_t)b * MP * 3;
  float* c_out = cen + (size_t)b * NSEL * 3;
  float px[E], py[E], pz[E], dd[E];
  int base = t * E;
  #pragma unroll
  for (int e = 0; e < E; ++e) {
    px[e] = p[(base + e) * 3 + 0];
    py[e] = p[(base + e) * 3 + 1];
    pz[e] = p[(base + e) * 3 + 2];
    dd[e] = INFINITY;
  }
  float cx = p[0], cy = p[1], cz = p[2];
  if (t == 0) { c_out[0] = cx; c_out[1] = cy; c_out[2] = cz; }
  int par = 0;
  for (int it = 1; it < NSEL; ++it) {
    float bd = -1.0f;
    int bidx = 0;
    {
      #pragma clang fp contract(off)
      #pragma unroll
      for (int e = 0; e < E; ++e) {
        float dx = px[e] - cx, dy = py[e] - cy, dz = pz[e] - cz;
        float nd = dx * dx;
        nd += dy * dy;
        nd += dz * dz;
        float d = fminf(dd[e], nd);
        dd[e] = d;
        if (d > bd) { bd = d; bidx = base + e; }  // strict > keeps lowest index on ties
      }
    }
    unsigned long long k =
        ((unsigned long long)__float_as_uint(bd) << 32) | (unsigned)(~bidx);
    wave_max_u64(k);
    if (lane == 63) kb[par][wv] = k;
    __syncthreads();
    unsigned long long g = kb[par][0];
    #pragma unroll
    for (int w = 1; w < W; ++w) {
      unsigned long long o = kb[par][w];
      if (o > g) g = o;
    }
    int widx = __builtin_amdgcn_readfirstlane((int)(~(unsigned)g));
    const float* cp = p + (size_t)widx * 3;
    cx = cp[0]; cy = cp[1]; cz = cp[2];
    if (t == 0) {
      c_out[it * 3 + 0] = cx;
      c_out[it * 3 + 1] = cy;
      c_out[it * 3 + 2] = cz;
    }
    par ^= 1;
  }
}

// ---------------- ball query: 64 nearest with d2 <= R2, ties by lower index ----------------
// One wave per center; ballot compaction into LDS, then 64 rounds of wave-min.
// Wave-min via DPP in complement domain: min(k) = ~max(~k); the invalidation
// sentinel ~0ull complements to 0, which never wins the max (also makes
// bound_ctrl's injected 0 harmless).
template <int MP>
__global__ __launch_bounds__(256) void nbr_kernel(const float* __restrict__ pts,
                                                  const float* __restrict__ cen, int S,
                                                  float R2, int* __restrict__ nbr) {
  constexpr int CAP = 1024;
  __shared__ unsigned long long buf[4][CAP];
  int t = threadIdx.x;
  int wv = t >> 6, lane = t & 63;
  int gw = blockIdx.x * 4 + wv;
  int b = gw / S, s = gw % S;
  const float* p = pts + (size_t)b * MP * 3;
  const float* c = cen + ((size_t)b * S + s) * 3;
  float cx = c[0], cy = c[1], cz = c[2];
  unsigned long long* bw = buf[wv];
  int cnt = 0;
  {
    #pragma clang fp contract(off)
    for (int i0 = 0; i0 < MP; i0 += 64) {
      int i = i0 + lane;
      float dx = p[i * 3 + 0] - cx;
      float dy = p[i * 3 + 1] - cy;
      float dz = p[i * 3 + 2] - cz;
      float d2 = dx * dx;
      d2 += dy * dy;
      d2 += dz * dz;
      bool in = (d2 <= R2);
      unsigned long long mask = __ballot(in);
      if (in) {
        int off = __popcll(mask & ((1ull << lane) - 1ull));
        int pos = cnt + off;
        if (pos < CAP)
          bw[pos] = ((unsigned long long)__float_as_uint(d2) << 32) | (unsigned)i;
      }
      cnt += __popcll(mask);
    }
  }
  if (cnt > CAP) cnt = CAP;
  __syncthreads();  // uniform; ensures LDS writes visible
  int out = -1;
  if (cnt <= 64) {
    if (lane < cnt) out = (int)(unsigned)bw[lane];
  } else {
    for (int r = 0; r < 64; ++r) {
      unsigned long long mk = ~0ull;
      int mj = -1;
      for (int j = lane; j < cnt; j += 64) {
        unsigned long long v = bw[j];
        if (v < mk) { mk = v; mj = j; }
      }
      unsigned long long kc = ~mk;
      wave_max_u64(kc);
      unsigned long long g = ~__shfl(kc, 63, 64);  // broadcast lane63 (readlane x2)
      if (mk == g && mj >= 0) bw[mj] = ~0ull;  // unique keys -> exactly one owner
      asm volatile("s_waitcnt lgkmcnt(0)" ::: "memory");
      if (lane == r) out = (int)(unsigned)g;
    }
  }
  nbr[((size_t)b * S + s) * 64 + lane] = out;
}

// ---------------- SA1 grouped MLP: feats[64][9] -> 64 -> 128, masked max over K ----------------
__global__ __launch_bounds__(128) void group1_kernel(
    const float* __restrict__ pos, const float* __restrict__ x,
    const float* __restrict__ c1, const int* __restrict__ nbr,
    const float* __restrict__ w0, const float* __restrict__ b0,
    const float* __restrict__ w1, const float* __restrict__ b1,
    float* __restrict__ h1out) {
  __shared__ float feats[64][12];
  __shared__ float hbuf[64][66];
  __shared__ int nb[64];
  __shared__ float cc[3];
  int t = threadIdx.x;
  int bs = blockIdx.x;  // b*S1 + s
  int b = bs >> 11;
  if (t < 64) nb[t] = nbr[(size_t)bs * 64 + t];
  if (t < 3) cc[t] = c1[(size_t)bs * 3 + t];
  __syncthreads();
  if (t < 64) {
    int n = nb[t];
    int ni = n >= 0 ? n : 0;
    const float* pp = pos + ((size_t)b * MM + ni) * 3;
    const float* xx = x + ((size_t)b * MM + ni) * 3;
    float p0 = pp[0], p1 = pp[1], p2 = pp[2];
    feats[t][0] = p0; feats[t][1] = p1; feats[t][2] = p2;
    feats[t][3] = xx[0]; feats[t][4] = xx[1]; feats[t][5] = xx[2];
    feats[t][6] = p0 - cc[0]; feats[t][7] = p1 - cc[1]; feats[t][8] = p2 - cc[2];
  }
  __syncthreads();
  // layer1: 9 -> 64; thread -> (k = t>>1, q = t&1), 32 channels each
  {
    int k = t >> 1, q = t & 1;
    float acc[32];
    #pragma unroll
    for (int i = 0; i < 32; ++i) acc[i] = b0[q * 32 + i];
    #pragma unroll
    for (int j = 0; j < 9; ++j) {
      float f = feats[k][j];
      #pragma unroll
      for (int i = 0; i < 32; ++i) acc[i] += f * w0[j * 64 + q * 32 + i];
    }
    #pragma unroll
    for (int i = 0; i < 32; ++i) hbuf[k][q * 32 + i] = tanhf(acc[i]);
  }
  __syncthreads();
  // layer2: 64 -> 128 + masked max over k
  {
    int ch = t;  // 0..127
    float w[64];
    #pragma unroll
    for (int j = 0; j < 64; ++j) w[j] = w1[j * 128 + ch];
    float bias = b1[ch];
    float mx = -INFINITY;
    for (int k = 0; k < 64; ++k) {
      if (nb[k] < 0) continue;  // uniform across block
      float a = bias;
      #pragma unroll
      for (int j = 0; j < 64; ++j) a += hbuf[k][j] * w[j];
      mx = fmaxf(mx, tanhf(a));
    }
    h1out[(size_t)bs * 128 + ch] = mx;
  }
}

// ---------------- SA2 grouped MLP: feats[64][131] -> 128 -> 256, masked max over K ----------------
__global__ __launch_bounds__(256) void group2_kernel(
    const float* __restrict__ h1, const float* __restrict__ c1,
    const float* __restrict__ c2, const int* __restrict__ nbr,
    const float* __restrict__ w0, const float* __restrict__ b0,
    const float* __restrict__ w1, const float* __restrict__ b1,
    float* __restrict__ h2out) {
  __shared__ float fb[64][132];  // feats (131) then reused as hidden (128)
  __shared__ int nb[64];
  __shared__ float cc[3];
  int t = threadIdx.x;
  int bs = blockIdx.x;  // b*S2 + s
  int b = bs >> 9;
  if (t < 64) nb[t] = nbr[(size_t)bs * 64 + t];
  if (t < 3) cc[t] = c2[(size_t)bs * 3 + t];
  __syncthreads();
  {
    int k = t >> 2, q = t & 3;
    int n = nb[k];
    int ni = n >= 0 ? n : 0;
    const float* hrow = h1 + ((size_t)b * SS1 + ni) * 128;
    #pragma unroll
    for (int i = 0; i < 32; ++i) fb[k][q * 32 + i] = hrow[q * 32 + i];
    if (q == 0) {
      const float* pr = c1 + ((size_t)b * SS1 + ni) * 3;
      fb[k][128] = pr[0] - cc[0];
      fb[k][129] = pr[1] - cc[1];
      fb[k][130] = pr[2] - cc[2];
    }
  }
  __syncthreads();
  // layer1: 131 -> 128; thread -> (k = t>>2, q = t&3), 32 channels each
  float acc[32];
  {
    int k = t >> 2, q = t & 3;
    #pragma unroll
    for (int i = 0; i < 32; ++i) acc[i] = b0[q * 32 + i];
    for (int j = 0; j < 131; ++j) {
      float f = fb[k][j];
      const float* wr = w0 + (size_t)j * 128 + q * 32;
      #pragma unroll
      for (int i = 0; i < 32; ++i) acc[i] += f * wr[i];
    }
  }
  __syncthreads();  // all reads of feats done
  {
    int k = t >> 2, q = t & 3;
    #pragma unroll
    for (int i = 0; i < 32; ++i) fb[k][q * 32 + i] = tanhf(acc[i]);
  }
  __syncthreads();
  // layer2: 128 -> 256 + masked max over k
  {
    int ch = t;  // 0..255
    float w[128];
    #pragma unroll
    for (int j = 0; j < 128; ++j) w[j] = w1[(size_t)j * 256 + ch];
    float bias = b1[ch];
    float mx = -INFINITY;
    for (int k = 0; k < 64; ++k) {
      if (nb[k] < 0) continue;
      float a = bias;
      #pragma unroll
      for (int j = 0; j < 128; ++j) a += fb[k][j] * w[j];
      mx = fmaxf(mx, tanhf(a));
    }
    h2out[(size_t)bs * 256 + ch] = mx;
  }
}

// ---------------- global max over centers ----------------
__global__ __launch_bounds__(256) void gmax_kernel(const float* __restrict__ h2,
                                                   float* __restrict__ out) {
  int b = blockIdx.x, c = threadIdx.x;
  float mx = -INFINITY;
  for (int s = 0; s < SS2; ++s)
    mx = fmaxf(mx, h2[((size_t)b * SS2 + s) * 256 + c]);
  out[(size_t)BB * MM * 128 + b * 256 + c] = mx;
}

extern "C" void kernel_launch(void* const* d_in, const int* in_sizes, int n_in,
                              void* d_out, int out_size, void* d_ws, size_t ws_size,
                              hipStream_t stream) {
  // Reference is pure float32: all inputs AND the output buffer are f32.
  const float* x    = (const float*)d_in[0];
  const float* pos  = (const float*)d_in[1];
  const float* lw0  = (const float*)d_in[2];
  const float* lb0  = (const float*)d_in[3];
  const float* lw1  = (const float*)d_in[4];
  const float* lb1  = (const float*)d_in[5];
  const float* lw2  = (const float*)d_in[6];
  const float* lb2  = (const float*)d_in[7];
  const float* g1w0 = (const float*)d_in[8];
  const float* g1b0 = (const float*)d_in[9];
  const float* g1w1 = (const float*)d_in[10];
  const float* g1b1 = (const float*)d_in[11];
  const float* g2w0 = (const float*)d_in[12];
  const float* g2b0 = (const float*)d_in[13];
  const float* g2w1 = (const float*)d_in[14];
  const float* g2b1 = (const float*)d_in[15];
  float* out = (float*)d_out;

  // Scratch lives inside the LOCAL output region of d_out (4,194,304 f32 =
  // 16,777,216 bytes); local_mlp_kernel runs LAST and overwrites all of it.
  // d_ws is not used (ws_size not guaranteed sufficient).
  char* sc = (char*)d_out;
  float* h1   = (float*)(sc + 0);        // 4*2048*128 f32 = 4,194,304 B
  float* h2   = (float*)(sc + 4194304);  // 4*512*256 f32  = 2,097,152 B
  float* c1   = (float*)(sc + 6291456);  // 4*2048*3 f32   =    98,304 B
  float* c2   = (float*)(sc + 6389760);  // 4*512*3 f32    =    24,576 B
  int*   nbr1 = (int*)(sc + 6414336);    // 4*2048*64 i32  = 2,097,152 B
  int*   nbr2 = (int*)(sc + 8511488);    // 4*512*64 i32   =   524,288 B (end 9,035,776)

  fps_kernel<MM, SS1, 512><<<BB, 512, 0, stream>>>(pos, c1);
  nbr_kernel<MM><<<BB * SS1 / 4, 256, 0, stream>>>(pos, c1, SS1, 0.04f, nbr1);
  group1_kernel<<<BB * SS1, 128, 0, stream>>>(pos, x, c1, nbr1, g1w0, g1b0, g1w1, g1b1, h1);
  fps_kernel<SS1, SS2, 512><<<BB, 512, 0, stream>>>(c1, c2);
  nbr_kernel<SS1><<<BB * SS2 / 4, 256, 0, stream>>>(c1, c2, SS2, 0.16f, nbr2);
  group2_kernel<<<BB * SS2, 256, 0, stream>>>(h1, c1, c2, nbr2, g2w0, g2b0, g2w1, g2b1, h2);
  gmax_kernel<<<BB, 256, 0, stream>>>(h2, out);
  local_mlp_kernel<<<BB * MM / 2, 256, 0, stream>>>(pos, lw0, lb0, lw1, lb1, lw2, lb2, out);
}